// Round 5
// baseline (2202.750 us; speedup 1.0000x reference)
//
#include <hip/hip_runtime.h>
#include <math.h>

#define B 256
#define LQ 300
#define V 20
#define CD 30
#define H 128
#define HH 64
#define TT 6
#define WN 48
#define WD 128
#define SLOPE 0.01f
#define START 4
#define STOP 5

__device__ __forceinline__ float fsig(float x) { return 1.0f / (1.0f + __expf(-x)); }
__device__ __forceinline__ float ftanh(float x) {
    x = fminf(fmaxf(x, -15.f), 15.f);
    float e = __expf(2.f * x);
    return (e - 1.f) / (e + 1.f);
}
__device__ __forceinline__ float lrelu(float x) { return x >= 0.f ? x : SLOPE * x; }

// ---------------- BiLSTM: one block per (sample, direction) ----------------
// gate = tid&3 (i,f,g,o), unit = tid>>2. Input projection precomputed per vocab
// entry (only V=20 distinct inputs) into LDS. One barrier per step (ping-pong h).
__global__ __launch_bounds__(256) void k_lstm(
    const int* __restrict__ chars, const int* __restrict__ length,
    const float* __restrict__ emb,
    const float* __restrict__ wihf, const float* __restrict__ whhf,
    const float* __restrict__ bihf, const float* __restrict__ bhhf,
    const float* __restrict__ wihb, const float* __restrict__ whhb,
    const float* __restrict__ bihb, const float* __restrict__ bhhb,
    float* __restrict__ lstm_out)
{
    __shared__ __align__(16) float emb_s[V * CD];
    __shared__ __align__(16) float pre_s[V * 256];
    __shared__ __align__(16) float h_s[2][HH];
    __shared__ int chars_s[LQ];
    int tid = threadIdx.x;
    int b = blockIdx.x >> 1;
    bool fwd = (blockIdx.x & 1) == 0;
    int gate = tid & 3, unit = tid >> 2;
    int row = gate * HH + unit;  // torch gate order i,f,g,o
    const float* wih = fwd ? wihf : wihb;
    const float* whh = fwd ? whhf : whhb;
    const float* bih = fwd ? bihf : bihb;
    const float* bhh = fwd ? bhhf : bhhb;
    for (int i = tid; i < V * CD; i += 256) emb_s[i] = emb[i];
    for (int i = tid; i < LQ; i += 256) chars_s[i] = chars[b * LQ + i];
    float wh[HH];
#pragma unroll
    for (int k = 0; k < HH; k++) wh[k] = whh[row * HH + k];
    float wi[CD];
#pragma unroll
    for (int k = 0; k < CD; k++) wi[k] = wih[row * CD + k];
    float bias = bih[row] + bhh[row];
    if (tid < 2 * HH) h_s[tid >> 6][tid & 63] = 0.f;
    int len = length[b];
    __syncthreads();
    // precompute vocab gate table
    for (int v = 0; v < V; ++v) {
        float a0 = bias, a1 = 0.f;
        const float* ev = emb_s + v * CD;
#pragma unroll
        for (int k = 0; k < CD; k += 2) {
            a0 = fmaf(wi[k], ev[k], a0);
            a1 = fmaf(wi[k + 1], ev[k + 1], a1);
        }
        pre_s[v * 256 + tid] = a0 + a1;
    }
    __syncthreads();
    float c = 0.f;
    int hofs = fwd ? 0 : HH;
    int lane = tid & 63, qbase = lane & ~3;
    int src0 = fwd ? 0 : (len - 1);
    float accx = pre_s[chars_s[src0] * 256 + tid];
    for (int t = 0; t < len; ++t) {
        int buf = t & 1;  // read h_s[buf], write h_s[1-buf]
        float acc_cur = accx;
        if (t + 1 < len) {
            int srcn = fwd ? (t + 1) : (len - 2 - t);
            accx = pre_s[chars_s[srcn] * 256 + tid];
        }
        const float4* hp4 = (const float4*)h_s[buf];
        float a0 = acc_cur, a1 = 0.f, a2 = 0.f, a3 = 0.f;
#pragma unroll
        for (int k4 = 0; k4 < 16; k4++) {
            float4 hv4 = hp4[k4];
            a0 = fmaf(wh[4 * k4], hv4.x, a0);
            a1 = fmaf(wh[4 * k4 + 1], hv4.y, a1);
            a2 = fmaf(wh[4 * k4 + 2], hv4.z, a2);
            a3 = fmaf(wh[4 * k4 + 3], hv4.w, a3);
        }
        float x = (a0 + a1) + (a2 + a3);
        // tanh(x) = 2*sigmoid(2x)-1 : one exp, no divergence
        float y = (gate == 2) ? 2.f * x : x;
        float s = 1.f / (1.f + __expf(-y));
        float a = (gate == 2) ? (2.f * s - 1.f) : s;
        float gi = __shfl(a, qbase + 0);
        float gf = __shfl(a, qbase + 1);
        float gg = __shfl(a, qbase + 2);
        float go = __shfl(a, qbase + 3);
        c = gf * c + gi * gg;
        float hv = go * ftanh(c);
        if (gate == 0) {
            int src = fwd ? t : (len - 1 - t);
            h_s[1 - buf][unit] = hv;
            lstm_out[((size_t)b * LQ + src) * H + hofs + unit] = hv;
        }
        __syncthreads();
    }
}

// ---------------- lstm_mapping: 2 row-groups x 8 rows per iter ----------------
__global__ __launch_bounds__(256) void k_lstm_map(
    const float* __restrict__ lstm_out, const int* __restrict__ length,
    const float* __restrict__ wl, const float* __restrict__ bl,
    float* __restrict__ cat)
{
    __shared__ __align__(16) float row_s[16][128];
    int tid = threadIdx.x;
    int b = blockIdx.x >> 1, half = blockIdx.x & 1;
    int h = tid & 127, g = tid >> 7;
    float w[128];
#pragma unroll
    for (int k = 0; k < 128; k++) w[k] = wl[h * 128 + k];
    float bias = bl[h];
    int len = length[b];
    const float* src = lstm_out + (size_t)b * LQ * H;
    float* dst = cat + (size_t)b * LQ * 256;
    int nrows = (len - half + 1) >> 1;  // t = half + 2*ri, ri < nrows
    for (int base = 0; base < nrows; base += 16) {
        __syncthreads();
        for (int i = tid; i < 16 * 128; i += 256) {
            int ri = i >> 7, k = i & 127;
            int rr = base + ri;
            if (rr < nrows) row_s[ri][k] = src[(size_t)(half + 2 * rr) * H + k];
        }
        __syncthreads();
        float acc[8];
#pragma unroll
        for (int r = 0; r < 8; r++) acc[r] = bias;
#pragma unroll
        for (int k4 = 0; k4 < 32; k4++) {
#pragma unroll
            for (int r = 0; r < 8; r++) {
                float4 x = ((const float4*)row_s[g * 8 + r])[k4];
                acc[r] = fmaf(w[4 * k4], x.x, acc[r]);
                acc[r] = fmaf(w[4 * k4 + 1], x.y, acc[r]);
                acc[r] = fmaf(w[4 * k4 + 2], x.z, acc[r]);
                acc[r] = fmaf(w[4 * k4 + 3], x.w, acc[r]);
            }
        }
#pragma unroll
        for (int r = 0; r < 8; r++) {
            int rr = base + g * 8 + r;
            if (rr < nrows) dst[(size_t)(half + 2 * rr) * 256 + h] = lrelu(acc[r]);
        }
    }
}

// ---------------- conv1 + bn + leaky + pool: [B,1,48,128] -> [B,16,12,32] ----------------
__global__ void k_conv1(const float* __restrict__ words,
                        const float* __restrict__ cw, const float* __restrict__ cb,
                        const float* __restrict__ bs, const float* __restrict__ bb,
                        float* __restrict__ p1)
{
    int idx = blockIdx.x * 256 + threadIdx.x;  // B*16*12*32
    int px = idx & 31;
    int t1 = idx >> 5;
    int py = t1 % 12;
    int t2 = t1 / 12;
    int oc = t2 & 15;
    int b = t2 >> 4;
    float w[9];
#pragma unroll
    for (int k = 0; k < 9; k++) w[k] = cw[oc * 9 + k];
    float patch[5][5];
    int iy0 = 4 * py - 1, ix0 = 4 * px - 1;
#pragma unroll
    for (int r = 0; r < 5; r++)
#pragma unroll
        for (int cc = 0; cc < 5; cc++) {
            int iy = iy0 + r, ix = ix0 + cc;
            patch[r][cc] = (iy >= 0 && iy < WN && ix >= 0 && ix < WD)
                               ? words[((size_t)b * WN + iy) * WD + ix] : 0.f;
        }
    float bias = cb[oc], s = bs[oc], sb = bb[oc];
    float best = -1e30f;
#pragma unroll
    for (int dy = 0; dy < 2; dy++)
#pragma unroll
        for (int dx = 0; dx < 2; dx++) {
            float acc = bias;
#pragma unroll
            for (int ky = 0; ky < 3; ky++)
#pragma unroll
                for (int kx = 0; kx < 3; kx++)
                    acc = fmaf(w[ky * 3 + kx], patch[2 * dy + ky][2 * dx + kx], acc);
            best = fmaxf(best, lrelu(acc * s + sb));
        }
    p1[idx] = best;
}

// ---------------- conv2: LDS-staged, 2 blocks/sample (16 oc each) ----------------
__global__ __launch_bounds__(256) void k_conv2(
    const float* __restrict__ p1,
    const float* __restrict__ cw, const float* __restrict__ cb,
    const float* __restrict__ bs, const float* __restrict__ bb,
    float* __restrict__ p2)
{
    __shared__ float in_s[16 * 14 * 34];  // padded [16][14][34]
    __shared__ float w_s[16 * 16 * 9];
    int tid = threadIdx.x;
    int b = blockIdx.x >> 1;
    int oh = (blockIdx.x & 1) << 4;  // oc base 0 or 16
    for (int i = tid; i < 16 * 14 * 34; i += 256) in_s[i] = 0.f;
    for (int i = tid; i < 16 * 16 * 9; i += 256) w_s[i] = cw[oh * 16 * 9 + i];
    __syncthreads();
    for (int i = tid; i < 16 * 12 * 32; i += 256) {
        int ic = i / 384;
        int r = i - ic * 384;
        int iy = r >> 5, ix = r & 31;
        in_s[ic * 476 + (iy + 1) * 34 + ix + 1] = p1[b * 6144 + i];
    }
    __syncthreads();
    int ocl = tid >> 4;       // 0..15
    int l16 = tid & 15;       // spatial lane
    float acc[6][4];
    float bias = cb[oh + ocl];
#pragma unroll
    for (int q = 0; q < 6; q++)
#pragma unroll
        for (int j = 0; j < 4; j++) acc[q][j] = bias;
    for (int ic = 0; ic < 16; ic++) {
        const float* wp = w_s + (ocl * 16 + ic) * 9;
        float w[9];
#pragma unroll
        for (int k = 0; k < 9; k++) w[k] = wp[k];
        const float* ip = in_s + ic * 476;
#pragma unroll
        for (int q = 0; q < 6; q++) {
            int sp = l16 + (q << 4);
            int py = sp >> 4, px = sp & 15;
            const float* pb = ip + (2 * py) * 34 + 2 * px;
            float patch[4][4];
#pragma unroll
            for (int r = 0; r < 4; r++)
#pragma unroll
                for (int cc = 0; cc < 4; cc++) patch[r][cc] = pb[r * 34 + cc];
#pragma unroll
            for (int dy = 0; dy < 2; dy++)
#pragma unroll
                for (int dx = 0; dx < 2; dx++) {
                    float a = 0.f;
#pragma unroll
                    for (int ky = 0; ky < 3; ky++)
#pragma unroll
                        for (int kx = 0; kx < 3; kx++)
                            a = fmaf(w[ky * 3 + kx], patch[dy + ky][dx + kx], a);
                    acc[q][dy * 2 + dx] += a;
                }
        }
    }
    float s = bs[oh + ocl], sb = bb[oh + ocl];
#pragma unroll
    for (int q = 0; q < 6; q++) {
        float best = -1e30f;
#pragma unroll
        for (int j = 0; j < 4; j++) best = fmaxf(best, lrelu(acc[q][j] * s + sb));
        int sp = l16 + (q << 4);
        p2[((size_t)b * 32 + oh + ocl) * 96 + sp] = best;
    }
}

// ---------------- conv3: LDS-staged, 2 blocks/sample (32 oc each) ----------------
__global__ __launch_bounds__(256) void k_conv3(
    const float* __restrict__ p2,
    const float* __restrict__ cw, const float* __restrict__ cb,
    const float* __restrict__ bs, const float* __restrict__ bb,
    float* __restrict__ p3)
{
    __shared__ float in_s[32 * 8 * 18];   // padded [32][8][18]
    __shared__ float w_s[32 * 32 * 9];
    int tid = threadIdx.x;
    int b = blockIdx.x >> 1;
    int oh = (blockIdx.x & 1) << 5;  // oc base 0 or 32
    for (int i = tid; i < 32 * 8 * 18; i += 256) in_s[i] = 0.f;
    for (int i = tid; i < 32 * 32 * 9; i += 256) w_s[i] = cw[oh * 32 * 9 + i];
    __syncthreads();
    for (int i = tid; i < 32 * 6 * 16; i += 256) {
        int ic = i / 96;
        int r = i - ic * 96;
        int iy = r >> 4, ix = r & 15;
        in_s[ic * 144 + (iy + 1) * 18 + ix + 1] = p2[b * 3072 + i];
    }
    __syncthreads();
    int ocl = tid >> 3;      // 0..31
    int l8 = tid & 7;
    float acc[3][4];
    float bias = cb[oh + ocl];
#pragma unroll
    for (int q = 0; q < 3; q++)
#pragma unroll
        for (int j = 0; j < 4; j++) acc[q][j] = bias;
    for (int ic = 0; ic < 32; ic++) {
        const float* wp = w_s + (ocl * 32 + ic) * 9;
        float w[9];
#pragma unroll
        for (int k = 0; k < 9; k++) w[k] = wp[k];
        const float* ip = in_s + ic * 144;
#pragma unroll
        for (int q = 0; q < 3; q++) {
            int sp = l8 + (q << 3);
            int py = sp >> 3, px = sp & 7;
            const float* pb = ip + (2 * py) * 18 + 2 * px;
            float patch[4][4];
#pragma unroll
            for (int r = 0; r < 4; r++)
#pragma unroll
                for (int cc = 0; cc < 4; cc++) patch[r][cc] = pb[r * 18 + cc];
#pragma unroll
            for (int dy = 0; dy < 2; dy++)
#pragma unroll
                for (int dx = 0; dx < 2; dx++) {
                    float a = 0.f;
#pragma unroll
                    for (int ky = 0; ky < 3; ky++)
#pragma unroll
                        for (int kx = 0; kx < 3; kx++)
                            a = fmaf(w[ky * 3 + kx], patch[dy + ky][dx + kx], a);
                    acc[q][dy * 2 + dx] += a;
                }
        }
    }
    float s = bs[oh + ocl], sb = bb[oh + ocl];
#pragma unroll
    for (int q = 0; q < 3; q++) {
        float best = -1e30f;
#pragma unroll
        for (int j = 0; j < 4; j++) best = fmaxf(best, lrelu(acc[q][j] * s + sb));
        int sp = l8 + (q << 3);
        p3[((size_t)b * 64 + oh + ocl) * 24 + sp] = best;
    }
}

// ---------------- cnn_mapping with the [B,128,300]->[B,300,128] reshape quirk ----------------
__global__ __launch_bounds__(256) void k_cnn_map(
    const float* __restrict__ p3, const int* __restrict__ length,
    const float* __restrict__ wlc, const float* __restrict__ blc,
    float* __restrict__ cat)
{
    __shared__ float flat_s[1536];
    __shared__ float w_s[3600];
    __shared__ float b_s[300];
    int tid = threadIdx.x, b = blockIdx.x;
    for (int i = tid; i < 1536; i += 256) flat_s[i] = p3[b * 1536 + i];
    for (int i = tid; i < 3600; i += 256) w_s[i] = wlc[i];
    for (int i = tid; i < 300; i += 256) b_s[i] = blc[i];
    int len = length[b];
    __syncthreads();
    int bound = len * 128;
    for (int j = tid; j < bound; j += 256) {
        int l = j >> 7, h = j & 127;
        int row = j / 300, col = j - row * 300;
        float acc = b_s[col];
#pragma unroll
        for (int k = 0; k < 12; k++) acc = fmaf(flat_s[row * 12 + k], w_s[col * 12 + k], acc);
        cat[((size_t)b * LQ + l) * 256 + H + h] = lrelu(acc);
    }
}

// ---------------- h1: 8 rows/iter, K split 2x128, weights in VGPRs ----------------
__global__ __launch_bounds__(256) void k_h1(
    const float* __restrict__ cat, const int* __restrict__ length,
    const float* __restrict__ w1, const float* __restrict__ b1,
    float* __restrict__ h1b)
{
    __shared__ __align__(16) float row_s[8][256];
    __shared__ float part_s[2][8][104];
    __shared__ float b_s[100];
    int tid = threadIdx.x;
    int b = blockIdx.x >> 1, half = blockIdx.x & 1;
    int lane = tid & 127, kh = tid >> 7;
    bool act = lane < 100;
    float w[128];
    if (act) {
#pragma unroll
        for (int k = 0; k < 128; k++) w[k] = w1[lane * 256 + kh * 128 + k];
    }
    if (tid < 100) b_s[tid] = b1[tid];
    int len = length[b];
    const float* src = cat + (size_t)b * LQ * 256;
    float* dst = h1b + (size_t)b * LQ * 100;
    int nrows = (len - half + 1) >> 1;
    for (int base = 0; base < nrows; base += 8) {
        __syncthreads();
        for (int i = tid; i < 8 * 256; i += 256) {
            int ri = i >> 8, k = i & 255;
            int rr = base + ri;
            if (rr < nrows) row_s[ri][k] = src[(size_t)(half + 2 * rr) * 256 + k];
        }
        __syncthreads();
        if (act) {
            float acc[8];
#pragma unroll
            for (int r = 0; r < 8; r++) acc[r] = 0.f;
#pragma unroll
            for (int k4 = 0; k4 < 32; k4++) {
#pragma unroll
                for (int r = 0; r < 8; r++) {
                    float4 x = ((const float4*)(row_s[r] + kh * 128))[k4];
                    acc[r] = fmaf(w[4 * k4], x.x, acc[r]);
                    acc[r] = fmaf(w[4 * k4 + 1], x.y, acc[r]);
                    acc[r] = fmaf(w[4 * k4 + 2], x.z, acc[r]);
                    acc[r] = fmaf(w[4 * k4 + 3], x.w, acc[r]);
                }
            }
#pragma unroll
            for (int r = 0; r < 8; r++) part_s[kh][r][lane] = acc[r];
        }
        __syncthreads();
        for (int i = tid; i < 800; i += 256) {
            int r = i / 100, o = i - r * 100;
            int rr = base + r;
            if (rr < nrows)
                dst[(size_t)(half + 2 * rr) * 100 + o] =
                    lrelu(b_s[o] + part_s[0][r][o] + part_s[1][r][o]);
        }
    }
}

// ---------------- h2 + logits: 8 rows/iter ----------------
__global__ __launch_bounds__(256) void k_h2_logits(
    const float* __restrict__ h1b, const int* __restrict__ length,
    const float* __restrict__ w2, const float* __restrict__ b2,
    const float* __restrict__ wt, const float* __restrict__ bt,
    float* __restrict__ logits)
{
    __shared__ __align__(16) float row_s[8][100];
    __shared__ float h2_s[8][100];
    __shared__ float wt_s[6 * 94];
    __shared__ float bt_s[6];
    int tid = threadIdx.x;
    int b = blockIdx.x >> 1, half = blockIdx.x & 1;
    float w[100];
    if (tid < 94) {
#pragma unroll
        for (int k = 0; k < 100; k++) w[k] = w2[tid * 100 + k];
    }
    float bias = (tid < 94) ? b2[tid] : 0.f;
    for (int i = tid; i < 564; i += 256) wt_s[i] = wt[i];
    if (tid < 6) bt_s[tid] = bt[tid];
    int len = length[b];
    const float* src = h1b + (size_t)b * LQ * 100;
    float* dst = logits + (size_t)b * LQ * TT;
    int nrows = (len - half + 1) >> 1;
    for (int base = 0; base < nrows; base += 8) {
        __syncthreads();
        for (int i = tid; i < 800; i += 256) {
            int r = i / 100, k = i - r * 100;
            int rr = base + r;
            if (rr < nrows) row_s[r][k] = src[(size_t)(half + 2 * rr) * 100 + k];
        }
        __syncthreads();
        if (tid < 94) {
            float acc[8];
#pragma unroll
            for (int r = 0; r < 8; r++) acc[r] = bias;
#pragma unroll
            for (int k4 = 0; k4 < 25; k4++) {
#pragma unroll
                for (int r = 0; r < 8; r++) {
                    float4 x = ((const float4*)row_s[r])[k4];
                    acc[r] = fmaf(w[4 * k4], x.x, acc[r]);
                    acc[r] = fmaf(w[4 * k4 + 1], x.y, acc[r]);
                    acc[r] = fmaf(w[4 * k4 + 2], x.z, acc[r]);
                    acc[r] = fmaf(w[4 * k4 + 3], x.w, acc[r]);
                }
            }
#pragma unroll
            for (int r = 0; r < 8; r++) h2_s[r][tid] = lrelu(acc[r]);
        }
        __syncthreads();
        if (tid < 48) {
            int r = tid / 6, tag = tid - r * 6;
            int rr = base + r;
            if (rr < nrows) {
                float a0 = bt_s[tag], a1 = 0.f;
#pragma unroll
                for (int k = 0; k < 94; k += 2) {
                    a0 = fmaf(wt_s[tag * 94 + k], h2_s[r][k], a0);
                    a1 = fmaf(wt_s[tag * 94 + k + 1], h2_s[r][k + 1], a1);
                }
                dst[(size_t)(half + 2 * rr) * TT + tag] = lrelu(a0 + a1);
            }
        }
    }
}

// ---------------- CRF: real score + alpha recursion, one wave per sample ----------------
__global__ __launch_bounds__(64) void k_crf(
    const float* __restrict__ logits, const int* __restrict__ tags,
    const int* __restrict__ length, const float* __restrict__ trans,
    float* __restrict__ crfv)
{
    int tid = threadIdx.x, b = blockIdx.x;
    int len = length[b];
    const int* tg = tags + b * LQ;
    float s = 0.f;
    for (int t = tid; t < len; t += 64) {
        int cur = tg[t];
        int prev = (t == 0) ? START : tg[t - 1];
        s += logits[((size_t)b * LQ + t) * TT + cur] + trans[prev * TT + cur];
    }
#pragma unroll
    for (int off = 32; off > 0; off >>= 1) s += __shfl_down(s, off);
    float real = __shfl(s, 0) + trans[tg[len - 1] * TT + STOP];
    int j = (tid < TT) ? tid : 0;
    float trc[TT];
#pragma unroll
    for (int i = 0; i < TT; i++) trc[i] = trans[i * TT + j];
    float tstop = trans[j * TT + STOP];
    float alpha = 0.f;
    for (int t = 0; t < len; ++t) {
        float lg = logits[((size_t)b * LQ + t) * TT + j];
        float a0 = __shfl(alpha, 0), a1 = __shfl(alpha, 1), a2 = __shfl(alpha, 2);
        float a3 = __shfl(alpha, 3), a4 = __shfl(alpha, 4), a5 = __shfl(alpha, 5);
        float v0 = a0 + trc[0], v1 = a1 + trc[1], v2 = a2 + trc[2];
        float v3 = a3 + trc[3], v4 = a4 + trc[4], v5 = a5 + trc[5];
        float m = fmaxf(fmaxf(fmaxf(v0, v1), fmaxf(v2, v3)), fmaxf(v4, v5));
        float sum = __expf(v0 - m) + __expf(v1 - m) + __expf(v2 - m) +
                    __expf(v3 - m) + __expf(v4 - m) + __expf(v5 - m);
        alpha = m + __logf(sum) + lg;
    }
    float v = alpha + tstop;
    float w0 = __shfl(v, 0), w1 = __shfl(v, 1), w2 = __shfl(v, 2);
    float w3 = __shfl(v, 3), w4 = __shfl(v, 4), w5 = __shfl(v, 5);
    float m2 = fmaxf(fmaxf(fmaxf(w0, w1), fmaxf(w2, w3)), fmaxf(w4, w5));
    float total = m2 + __logf(__expf(w0 - m2) + __expf(w1 - m2) + __expf(w2 - m2) +
                              __expf(w3 - m2) + __expf(w4 - m2) + __expf(w5 - m2));
    if (tid == 0) crfv[b] = total - real;
}

__global__ void k_sum(const float* __restrict__ crfv, float* __restrict__ out)
{
    __shared__ float red[4];
    int tid = threadIdx.x;
    float v = crfv[tid];
#pragma unroll
    for (int off = 32; off > 0; off >>= 1) v += __shfl_down(v, off);
    if ((tid & 63) == 0) red[tid >> 6] = v;
    __syncthreads();
    if (tid == 0) out[0] = red[0] + red[1] + red[2] + red[3];
}

extern "C" void kernel_launch(void* const* d_in, const int* in_sizes, int n_in,
                              void* d_out, int out_size, void* d_ws, size_t ws_size,
                              hipStream_t stream)
{
    const int* characters = (const int*)d_in[0];
    const int* tags       = (const int*)d_in[1];
    const int* length     = (const int*)d_in[2];
    const float* words    = (const float*)d_in[3];
    const float* emb      = (const float*)d_in[4];
    const float* w_ih_f   = (const float*)d_in[5];
    const float* w_hh_f   = (const float*)d_in[6];
    const float* b_ih_f   = (const float*)d_in[7];
    const float* b_hh_f   = (const float*)d_in[8];
    const float* w_ih_b   = (const float*)d_in[9];
    const float* w_hh_b   = (const float*)d_in[10];
    const float* b_ih_b   = (const float*)d_in[11];
    const float* b_hh_b   = (const float*)d_in[12];
    const float* w_lin_lstm = (const float*)d_in[13];
    const float* b_lin_lstm = (const float*)d_in[14];
    const float* conv1_w  = (const float*)d_in[15];
    const float* conv1_b  = (const float*)d_in[16];
    const float* bn1_s    = (const float*)d_in[17];
    const float* bn1_b    = (const float*)d_in[18];
    const float* conv2_w  = (const float*)d_in[19];
    const float* conv2_b  = (const float*)d_in[20];
    const float* bn2_s    = (const float*)d_in[21];
    const float* bn2_b    = (const float*)d_in[22];
    const float* conv3_w  = (const float*)d_in[23];
    const float* conv3_b  = (const float*)d_in[24];
    const float* bn3_s    = (const float*)d_in[25];
    const float* bn3_b    = (const float*)d_in[26];
    const float* w_lin_cnn = (const float*)d_in[27];
    const float* b_lin_cnn = (const float*)d_in[28];
    const float* w1       = (const float*)d_in[29];
    const float* b1       = (const float*)d_in[30];
    const float* w2       = (const float*)d_in[31];
    const float* b2       = (const float*)d_in[32];
    const float* w_tag    = (const float*)d_in[33];
    const float* b_tag    = (const float*)d_in[34];
    const float* trans    = (const float*)d_in[35];

    float* ws = (float*)d_ws;
    float* lstm_out = ws;                                  // B*L*H
    float* cat      = lstm_out + (size_t)B * LQ * H;       // B*L*256
    float* p1       = cat + (size_t)B * LQ * 256;          // B*16*12*32
    float* p2       = p1 + (size_t)B * 16 * 12 * 32;       // B*32*6*16
    float* p3       = p2 + (size_t)B * 32 * 6 * 16;        // B*1536
    float* logits   = p3 + (size_t)B * 1536;               // B*L*6
    float* crfv     = logits + (size_t)B * LQ * TT;        // 256
    float* h1b      = lstm_out;  // reuse: lstm_out dead after k_lstm_map

    k_lstm<<<512, 256, 0, stream>>>(characters, length, emb,
                                    w_ih_f, w_hh_f, b_ih_f, b_hh_f,
                                    w_ih_b, w_hh_b, b_ih_b, b_hh_b, lstm_out);
    k_conv1<<<6144, 256, 0, stream>>>(words, conv1_w, conv1_b, bn1_s, bn1_b, p1);
    k_conv2<<<512, 256, 0, stream>>>(p1, conv2_w, conv2_b, bn2_s, bn2_b, p2);
    k_conv3<<<512, 256, 0, stream>>>(p2, conv3_w, conv3_b, bn3_s, bn3_b, p3);
    k_lstm_map<<<512, 256, 0, stream>>>(lstm_out, length, w_lin_lstm, b_lin_lstm, cat);
    k_cnn_map<<<256, 256, 0, stream>>>(p3, length, w_lin_cnn, b_lin_cnn, cat);
    k_h1<<<512, 256, 0, stream>>>(cat, length, w1, b1, h1b);
    k_h2_logits<<<512, 256, 0, stream>>>(h1b, length, w2, b2, w_tag, b_tag, logits);
    k_crf<<<256, 64, 0, stream>>>(logits, tags, length, trans, crfv);
    k_sum<<<1, 256, 0, stream>>>(crfv, (float*)d_out);
}

// Round 8
// 935.994 us; speedup vs baseline: 2.3534x; 2.3534x over previous
//
#include <hip/hip_runtime.h>
#include <math.h>

#define B 256
#define LQ 300
#define V 20
#define CD 30
#define H 128
#define HH 64
#define TT 6
#define WN 48
#define WD 128
#define SLOPE 0.01f
#define START 4
#define STOP 5

__device__ __forceinline__ float fsig(float x) { return 1.0f / (1.0f + __expf(-x)); }
__device__ __forceinline__ float ftanh(float x) {
    x = fminf(fmaxf(x, -15.f), 15.f);
    float e = __expf(2.f * x);
    return (e - 1.f) / (e + 1.f);
}
__device__ __forceinline__ float lrelu(float x) { return x >= 0.f ? x : SLOPE * x; }

// ---------------- BiLSTM: one block per (sample, direction) ----------------
__global__ __launch_bounds__(256) void k_lstm(
    const int* __restrict__ chars, const int* __restrict__ length,
    const float* __restrict__ emb,
    const float* __restrict__ wihf, const float* __restrict__ whhf,
    const float* __restrict__ bihf, const float* __restrict__ bhhf,
    const float* __restrict__ wihb, const float* __restrict__ whhb,
    const float* __restrict__ bihb, const float* __restrict__ bhhb,
    float* __restrict__ lstm_out)
{
    __shared__ __align__(16) float emb_s[V * CD];
    __shared__ __align__(16) float pre_s[V * 256];
    __shared__ __align__(16) float h_s[2][HH];
    __shared__ int chars_s[LQ];
    int tid = threadIdx.x;
    int b = blockIdx.x >> 1;
    bool fwd = (blockIdx.x & 1) == 0;
    int gate = tid & 3, unit = tid >> 2;
    int row = gate * HH + unit;  // torch gate order i,f,g,o
    const float* wih = fwd ? wihf : wihb;
    const float* whh = fwd ? whhf : whhb;
    const float* bih = fwd ? bihf : bihb;
    const float* bhh = fwd ? bhhf : bhhb;
    for (int i = tid; i < V * CD; i += 256) emb_s[i] = emb[i];
    for (int i = tid; i < LQ; i += 256) chars_s[i] = chars[b * LQ + i];
    float wh[HH];
#pragma unroll
    for (int k = 0; k < HH; k++) wh[k] = whh[row * HH + k];
    float wi[CD];
#pragma unroll
    for (int k = 0; k < CD; k++) wi[k] = wih[row * CD + k];
    float bias = bih[row] + bhh[row];
    if (tid < 2 * HH) h_s[tid >> 6][tid & 63] = 0.f;
    int len = length[b];
    __syncthreads();
    // precompute vocab gate table (only V=20 distinct inputs)
    for (int v = 0; v < V; ++v) {
        float a0 = bias, a1 = 0.f;
        const float* ev = emb_s + v * CD;
#pragma unroll
        for (int k = 0; k < CD; k += 2) {
            a0 = fmaf(wi[k], ev[k], a0);
            a1 = fmaf(wi[k + 1], ev[k + 1], a1);
        }
        pre_s[v * 256 + tid] = a0 + a1;
    }
    __syncthreads();
    float c = 0.f;
    int hofs = fwd ? 0 : HH;
    int lane = tid & 63, qbase = lane & ~3;
    int src0 = fwd ? 0 : (len - 1);
    float accx = pre_s[chars_s[src0] * 256 + tid];
    for (int t = 0; t < len; ++t) {
        int buf = t & 1;  // read h_s[buf], write h_s[1-buf]
        float acc_cur = accx;
        if (t + 1 < len) {
            int srcn = fwd ? (t + 1) : (len - 2 - t);
            accx = pre_s[chars_s[srcn] * 256 + tid];
        }
        const float4* hp4 = (const float4*)h_s[buf];
        float a0 = acc_cur, a1 = 0.f, a2 = 0.f, a3 = 0.f;
#pragma unroll
        for (int k4 = 0; k4 < 16; k4++) {
            float4 hv4 = hp4[k4];
            a0 = fmaf(wh[4 * k4], hv4.x, a0);
            a1 = fmaf(wh[4 * k4 + 1], hv4.y, a1);
            a2 = fmaf(wh[4 * k4 + 2], hv4.z, a2);
            a3 = fmaf(wh[4 * k4 + 3], hv4.w, a3);
        }
        float x = (a0 + a1) + (a2 + a3);
        float y = (gate == 2) ? 2.f * x : x;
        float s = 1.f / (1.f + __expf(-y));
        float a = (gate == 2) ? (2.f * s - 1.f) : s;
        float gi = __shfl(a, qbase + 0);
        float gf = __shfl(a, qbase + 1);
        float gg = __shfl(a, qbase + 2);
        float go = __shfl(a, qbase + 3);
        c = gf * c + gi * gg;
        float hv = go * ftanh(c);
        if (gate == 0) {
            int src = fwd ? t : (len - 1 - t);
            h_s[1 - buf][unit] = hv;
            lstm_out[((size_t)b * LQ + src) * H + hofs + unit] = hv;
        }
        __syncthreads();
    }
}

// ---------------- lstm_mapping: K split 2x64 (w[64]/thread, no spill), 8 rows/iter ----------------
__global__ __launch_bounds__(256) void k_lstm_map(
    const float* __restrict__ lstm_out, const int* __restrict__ length,
    const float* __restrict__ wl, const float* __restrict__ bl,
    float* __restrict__ cat)
{
    __shared__ __align__(16) float row_s[8][128];
    __shared__ float part_s[2][8][128];
    __shared__ float b_s[128];
    int tid = threadIdx.x;
    int b = blockIdx.x >> 1, half = blockIdx.x & 1;
    int h = tid & 127, kh = tid >> 7;
    float w[64];
#pragma unroll
    for (int k = 0; k < 64; k++) w[k] = wl[h * 128 + kh * 64 + k];
    if (tid < 128) b_s[tid] = bl[tid];
    int len = length[b];
    const float* src = lstm_out + (size_t)b * LQ * H;
    float* dst = cat + (size_t)b * LQ * 256;
    int nrows = (len - half + 1) >> 1;  // t = half + 2*ri
    for (int base = 0; base < nrows; base += 8) {
        __syncthreads();
        for (int i = tid; i < 8 * 128; i += 256) {
            int ri = i >> 7, k = i & 127;
            int rr = base + ri;
            if (rr < nrows) row_s[ri][k] = src[(size_t)(half + 2 * rr) * H + k];
        }
        __syncthreads();
        float acc[8];
#pragma unroll
        for (int r = 0; r < 8; r++) acc[r] = 0.f;
#pragma unroll 2
        for (int k4 = 0; k4 < 16; k4++) {
#pragma unroll
            for (int r = 0; r < 8; r++) {
                float4 x = ((const float4*)(row_s[r] + kh * 64))[k4];
                acc[r] = fmaf(w[4 * k4], x.x, acc[r]);
                acc[r] = fmaf(w[4 * k4 + 1], x.y, acc[r]);
                acc[r] = fmaf(w[4 * k4 + 2], x.z, acc[r]);
                acc[r] = fmaf(w[4 * k4 + 3], x.w, acc[r]);
            }
        }
#pragma unroll
        for (int r = 0; r < 8; r++) part_s[kh][r][h] = acc[r];
        __syncthreads();
        for (int i = tid; i < 1024; i += 256) {
            int r = i >> 7, o = i & 127;
            int rr = base + r;
            if (rr < nrows)
                dst[(size_t)(half + 2 * rr) * 256 + o] =
                    lrelu(b_s[o] + part_s[0][r][o] + part_s[1][r][o]);
        }
    }
}

// ---------------- conv1 + bn + leaky + pool: [B,1,48,128] -> [B,16,12,32] ----------------
__global__ void k_conv1(const float* __restrict__ words,
                        const float* __restrict__ cw, const float* __restrict__ cb,
                        const float* __restrict__ bs, const float* __restrict__ bb,
                        float* __restrict__ p1)
{
    int idx = blockIdx.x * 256 + threadIdx.x;  // B*16*12*32
    int px = idx & 31;
    int t1 = idx >> 5;
    int py = t1 % 12;
    int t2 = t1 / 12;
    int oc = t2 & 15;
    int b = t2 >> 4;
    float w[9];
#pragma unroll
    for (int k = 0; k < 9; k++) w[k] = cw[oc * 9 + k];
    float patch[5][5];
    int iy0 = 4 * py - 1, ix0 = 4 * px - 1;
#pragma unroll
    for (int r = 0; r < 5; r++)
#pragma unroll
        for (int cc = 0; cc < 5; cc++) {
            int iy = iy0 + r, ix = ix0 + cc;
            patch[r][cc] = (iy >= 0 && iy < WN && ix >= 0 && ix < WD)
                               ? words[((size_t)b * WN + iy) * WD + ix] : 0.f;
        }
    float bias = cb[oc], s = bs[oc], sb = bb[oc];
    float best = -1e30f;
#pragma unroll
    for (int dy = 0; dy < 2; dy++)
#pragma unroll
        for (int dx = 0; dx < 2; dx++) {
            float acc = bias;
#pragma unroll
            for (int ky = 0; ky < 3; ky++)
#pragma unroll
                for (int kx = 0; kx < 3; kx++)
                    acc = fmaf(w[ky * 3 + kx], patch[2 * dy + ky][2 * dx + kx], acc);
            best = fmaxf(best, lrelu(acc * s + sb));
        }
    p1[idx] = best;
}

// ---------------- conv2: LDS-staged, 2 blocks/sample (16 oc each) ----------------
__global__ __launch_bounds__(256) void k_conv2(
    const float* __restrict__ p1,
    const float* __restrict__ cw, const float* __restrict__ cb,
    const float* __restrict__ bs, const float* __restrict__ bb,
    float* __restrict__ p2)
{
    __shared__ float in_s[16 * 14 * 34];  // padded [16][14][34]
    __shared__ float w_s[16 * 16 * 9];
    int tid = threadIdx.x;
    int b = blockIdx.x >> 1;
    int oh = (blockIdx.x & 1) << 4;  // oc base 0 or 16
    for (int i = tid; i < 16 * 14 * 34; i += 256) in_s[i] = 0.f;
    for (int i = tid; i < 16 * 16 * 9; i += 256) w_s[i] = cw[oh * 16 * 9 + i];
    __syncthreads();
    for (int i = tid; i < 16 * 12 * 32; i += 256) {
        int ic = i / 384;
        int r = i - ic * 384;
        int iy = r >> 5, ix = r & 31;
        in_s[ic * 476 + (iy + 1) * 34 + ix + 1] = p1[b * 6144 + i];
    }
    __syncthreads();
    int ocl = tid >> 4;       // 0..15
    int l16 = tid & 15;       // spatial lane
    float acc[6][4];
    float bias = cb[oh + ocl];
#pragma unroll
    for (int q = 0; q < 6; q++)
#pragma unroll
        for (int j = 0; j < 4; j++) acc[q][j] = bias;
    for (int ic = 0; ic < 16; ic++) {
        const float* wp = w_s + (ocl * 16 + ic) * 9;
        float w[9];
#pragma unroll
        for (int k = 0; k < 9; k++) w[k] = wp[k];
        const float* ip = in_s + ic * 476;
#pragma unroll
        for (int q = 0; q < 6; q++) {
            int sp = l16 + (q << 4);
            int py = sp >> 4, px = sp & 15;
            const float* pb = ip + (2 * py) * 34 + 2 * px;
            float patch[4][4];
#pragma unroll
            for (int r = 0; r < 4; r++)
#pragma unroll
                for (int cc = 0; cc < 4; cc++) patch[r][cc] = pb[r * 34 + cc];
#pragma unroll
            for (int dy = 0; dy < 2; dy++)
#pragma unroll
                for (int dx = 0; dx < 2; dx++) {
                    float a = 0.f;
#pragma unroll
                    for (int ky = 0; ky < 3; ky++)
#pragma unroll
                        for (int kx = 0; kx < 3; kx++)
                            a = fmaf(w[ky * 3 + kx], patch[dy + ky][dx + kx], a);
                    acc[q][dy * 2 + dx] += a;
                }
        }
    }
    float s = bs[oh + ocl], sb = bb[oh + ocl];
#pragma unroll
    for (int q = 0; q < 6; q++) {
        float best = -1e30f;
#pragma unroll
        for (int j = 0; j < 4; j++) best = fmaxf(best, lrelu(acc[q][j] * s + sb));
        int sp = l16 + (q << 4);
        p2[((size_t)b * 32 + oh + ocl) * 96 + sp] = best;
    }
}

// ---------------- conv3: LDS-staged, 2 blocks/sample (32 oc each) ----------------
__global__ __launch_bounds__(256) void k_conv3(
    const float* __restrict__ p2,
    const float* __restrict__ cw, const float* __restrict__ cb,
    const float* __restrict__ bs, const float* __restrict__ bb,
    float* __restrict__ p3)
{
    __shared__ float in_s[32 * 8 * 18];   // padded [32][8][18]
    __shared__ float w_s[32 * 32 * 9];
    int tid = threadIdx.x;
    int b = blockIdx.x >> 1;
    int oh = (blockIdx.x & 1) << 5;  // oc base 0 or 32
    for (int i = tid; i < 32 * 8 * 18; i += 256) in_s[i] = 0.f;
    for (int i = tid; i < 32 * 32 * 9; i += 256) w_s[i] = cw[oh * 32 * 9 + i];
    __syncthreads();
    for (int i = tid; i < 32 * 6 * 16; i += 256) {
        int ic = i / 96;
        int r = i - ic * 96;
        int iy = r >> 4, ix = r & 15;
        in_s[ic * 144 + (iy + 1) * 18 + ix + 1] = p2[b * 3072 + i];
    }
    __syncthreads();
    int ocl = tid >> 3;      // 0..31
    int l8 = tid & 7;
    float acc[3][4];
    float bias = cb[oh + ocl];
#pragma unroll
    for (int q = 0; q < 3; q++)
#pragma unroll
        for (int j = 0; j < 4; j++) acc[q][j] = bias;
    for (int ic = 0; ic < 32; ic++) {
        const float* wp = w_s + (ocl * 32 + ic) * 9;
        float w[9];
#pragma unroll
        for (int k = 0; k < 9; k++) w[k] = wp[k];
        const float* ip = in_s + ic * 144;
#pragma unroll
        for (int q = 0; q < 3; q++) {
            int sp = l8 + (q << 3);
            int py = sp >> 3, px = sp & 7;
            const float* pb = ip + (2 * py) * 18 + 2 * px;
            float patch[4][4];
#pragma unroll
            for (int r = 0; r < 4; r++)
#pragma unroll
                for (int cc = 0; cc < 4; cc++) patch[r][cc] = pb[r * 18 + cc];
#pragma unroll
            for (int dy = 0; dy < 2; dy++)
#pragma unroll
                for (int dx = 0; dx < 2; dx++) {
                    float a = 0.f;
#pragma unroll
                    for (int ky = 0; ky < 3; ky++)
#pragma unroll
                        for (int kx = 0; kx < 3; kx++)
                            a = fmaf(w[ky * 3 + kx], patch[dy + ky][dx + kx], a);
                    acc[q][dy * 2 + dx] += a;
                }
        }
    }
    float s = bs[oh + ocl], sb = bb[oh + ocl];
#pragma unroll
    for (int q = 0; q < 3; q++) {
        float best = -1e30f;
#pragma unroll
        for (int j = 0; j < 4; j++) best = fmaxf(best, lrelu(acc[q][j] * s + sb));
        int sp = l8 + (q << 3);
        p3[((size_t)b * 64 + oh + ocl) * 24 + sp] = best;
    }
}

// ---------------- cnn_mapping with the [B,128,300]->[B,300,128] reshape quirk ----------------
__global__ __launch_bounds__(256) void k_cnn_map(
    const float* __restrict__ p3, const int* __restrict__ length,
    const float* __restrict__ wlc, const float* __restrict__ blc,
    float* __restrict__ cat)
{
    __shared__ float flat_s[1536];
    __shared__ float w_s[3600];
    __shared__ float b_s[300];
    int tid = threadIdx.x, b = blockIdx.x;
    for (int i = tid; i < 1536; i += 256) flat_s[i] = p3[b * 1536 + i];
    for (int i = tid; i < 3600; i += 256) w_s[i] = wlc[i];
    for (int i = tid; i < 300; i += 256) b_s[i] = blc[i];
    int len = length[b];
    __syncthreads();
    int bound = len * 128;
    for (int j = tid; j < bound; j += 256) {
        int l = j >> 7, h = j & 127;
        int row = j / 300, col = j - row * 300;
        float acc = b_s[col];
#pragma unroll
        for (int k = 0; k < 12; k++) acc = fmaf(flat_s[row * 12 + k], w_s[col * 12 + k], acc);
        cat[((size_t)b * LQ + l) * 256 + H + h] = lrelu(acc);
    }
}

// ---------------- h1: K split 4x64 (w[64]/thread, no spill), 8 rows/iter, 512 threads ----------------
__global__ __launch_bounds__(512) void k_h1(
    const float* __restrict__ cat, const int* __restrict__ length,
    const float* __restrict__ w1, const float* __restrict__ b1,
    float* __restrict__ h1b)
{
    __shared__ __align__(16) float row_s[8][256];
    __shared__ float part_s[4][8][104];
    __shared__ float b_s[100];
    int tid = threadIdx.x;
    int b = blockIdx.x >> 1, half = blockIdx.x & 1;
    int lane = tid & 127, q = tid >> 7;  // q = K quarter 0..3
    bool act = lane < 100;
    float w[64];
    if (act) {
#pragma unroll
        for (int k = 0; k < 64; k++) w[k] = w1[lane * 256 + q * 64 + k];
    }
    if (tid < 100) b_s[tid] = b1[tid];
    int len = length[b];
    const float* src = cat + (size_t)b * LQ * 256;
    float* dst = h1b + (size_t)b * LQ * 100;
    int nrows = (len - half + 1) >> 1;
    for (int base = 0; base < nrows; base += 8) {
        __syncthreads();
        for (int i = tid; i < 8 * 256; i += 512) {
            int ri = i >> 8, k = i & 255;
            int rr = base + ri;
            if (rr < nrows) row_s[ri][k] = src[(size_t)(half + 2 * rr) * 256 + k];
        }
        __syncthreads();
        if (act) {
            float acc[8];
#pragma unroll
            for (int r = 0; r < 8; r++) acc[r] = 0.f;
#pragma unroll 2
            for (int k4 = 0; k4 < 16; k4++) {
#pragma unroll
                for (int r = 0; r < 8; r++) {
                    float4 x = ((const float4*)(row_s[r] + q * 64))[k4];
                    acc[r] = fmaf(w[4 * k4], x.x, acc[r]);
                    acc[r] = fmaf(w[4 * k4 + 1], x.y, acc[r]);
                    acc[r] = fmaf(w[4 * k4 + 2], x.z, acc[r]);
                    acc[r] = fmaf(w[4 * k4 + 3], x.w, acc[r]);
                }
            }
#pragma unroll
            for (int r = 0; r < 8; r++) part_s[q][r][lane] = acc[r];
        }
        __syncthreads();
        for (int i = tid; i < 800; i += 512) {
            int r = i / 100, o = i - r * 100;
            int rr = base + r;
            if (rr < nrows)
                dst[(size_t)(half + 2 * rr) * 100 + o] =
                    lrelu(b_s[o] + (part_s[0][r][o] + part_s[1][r][o]) +
                          (part_s[2][r][o] + part_s[3][r][o]));
        }
    }
}

// ---------------- h2 + logits: K split 2x52 zero-padded, 8 rows/iter ----------------
__global__ __launch_bounds__(256) void k_h2_logits(
    const float* __restrict__ h1b, const int* __restrict__ length,
    const float* __restrict__ w2, const float* __restrict__ b2,
    const float* __restrict__ wt, const float* __restrict__ bt,
    float* __restrict__ logits)
{
    __shared__ __align__(16) float row_s[8][104];   // K=100 padded to 104 (zeros)
    __shared__ float part_s[2][8][96];
    __shared__ float h2_s[8][96];
    __shared__ float wt_s[6 * 94];
    __shared__ float bt_s[6];
    __shared__ float b2_s[94];
    int tid = threadIdx.x;
    int b = blockIdx.x >> 1, half = blockIdx.x & 1;
    int o = tid & 127, kh = tid >> 7;
    bool act = o < 94;
    int kbase = kh * 52;  // kh=0: k 0..51, kh=1: k 52..103 (100..103 are zero pad)
    float w[52];
    if (act) {
#pragma unroll
        for (int k = 0; k < 52; k++)
            w[k] = (kbase + k < 100) ? w2[o * 100 + kbase + k] : 0.f;
    }
    if (tid < 94) b2_s[tid] = b2[tid];
    for (int i = tid; i < 564; i += 256) wt_s[i] = wt[i];
    if (tid < 6) bt_s[tid] = bt[tid];
    int len = length[b];
    const float* src = h1b + (size_t)b * LQ * 100;
    float* dst = logits + (size_t)b * LQ * TT;
    int nrows = (len - half + 1) >> 1;
    for (int base = 0; base < nrows; base += 8) {
        __syncthreads();
        for (int i = tid; i < 8 * 104; i += 256) {
            int r = i / 104, k = i - r * 104;
            int rr = base + r;
            row_s[r][k] = (k < 100 && rr < nrows) ? src[(size_t)(half + 2 * rr) * 100 + k] : 0.f;
        }
        __syncthreads();
        if (act) {
            float acc[8];
#pragma unroll
            for (int r = 0; r < 8; r++) acc[r] = 0.f;
#pragma unroll 2
            for (int k4 = 0; k4 < 13; k4++) {
#pragma unroll
                for (int r = 0; r < 8; r++) {
                    float4 x = ((const float4*)(row_s[r] + kbase))[k4];
                    acc[r] = fmaf(w[4 * k4], x.x, acc[r]);
                    acc[r] = fmaf(w[4 * k4 + 1], x.y, acc[r]);
                    acc[r] = fmaf(w[4 * k4 + 2], x.z, acc[r]);
                    acc[r] = fmaf(w[4 * k4 + 3], x.w, acc[r]);
                }
            }
#pragma unroll
            for (int r = 0; r < 8; r++) part_s[kh][r][o] = acc[r];
        }
        __syncthreads();
        for (int i = tid; i < 752; i += 256) {
            int r = i / 94, oo = i - r * 94;
            h2_s[r][oo] = lrelu(b2_s[oo] + part_s[0][r][oo] + part_s[1][r][oo]);
        }
        __syncthreads();
        if (tid < 48) {
            int r = tid / 6, tag = tid - r * 6;
            int rr = base + r;
            if (rr < nrows) {
                float a0 = bt_s[tag], a1 = 0.f;
#pragma unroll
                for (int k = 0; k < 94; k += 2) {
                    a0 = fmaf(wt_s[tag * 94 + k], h2_s[r][k], a0);
                    a1 = fmaf(wt_s[tag * 94 + k + 1], h2_s[r][k + 1], a1);
                }
                dst[(size_t)(half + 2 * rr) * TT + tag] = lrelu(a0 + a1);
            }
        }
    }
}

// ---------------- CRF: real score + alpha recursion, one wave per sample ----------------
__global__ __launch_bounds__(64) void k_crf(
    const float* __restrict__ logits, const int* __restrict__ tags,
    const int* __restrict__ length, const float* __restrict__ trans,
    float* __restrict__ crfv)
{
    int tid = threadIdx.x, b = blockIdx.x;
    int len = length[b];
    const int* tg = tags + b * LQ;
    float s = 0.f;
    for (int t = tid; t < len; t += 64) {
        int cur = tg[t];
        int prev = (t == 0) ? START : tg[t - 1];
        s += logits[((size_t)b * LQ + t) * TT + cur] + trans[prev * TT + cur];
    }
#pragma unroll
    for (int off = 32; off > 0; off >>= 1) s += __shfl_down(s, off);
    float real = __shfl(s, 0) + trans[tg[len - 1] * TT + STOP];
    int j = (tid < TT) ? tid : 0;
    float trc[TT];
#pragma unroll
    for (int i = 0; i < TT; i++) trc[i] = trans[i * TT + j];
    float tstop = trans[j * TT + STOP];
    float alpha = 0.f;
    for (int t = 0; t < len; ++t) {
        float lg = logits[((size_t)b * LQ + t) * TT + j];
        float a0 = __shfl(alpha, 0), a1 = __shfl(alpha, 1), a2 = __shfl(alpha, 2);
        float a3 = __shfl(alpha, 3), a4 = __shfl(alpha, 4), a5 = __shfl(alpha, 5);
        float v0 = a0 + trc[0], v1 = a1 + trc[1], v2 = a2 + trc[2];
        float v3 = a3 + trc[3], v4 = a4 + trc[4], v5 = a5 + trc[5];
        float m = fmaxf(fmaxf(fmaxf(v0, v1), fmaxf(v2, v3)), fmaxf(v4, v5));
        float sum = __expf(v0 - m) + __expf(v1 - m) + __expf(v2 - m) +
                    __expf(v3 - m) + __expf(v4 - m) + __expf(v5 - m);
        alpha = m + __logf(sum) + lg;
    }
    float v = alpha + tstop;
    float w0 = __shfl(v, 0), w1 = __shfl(v, 1), w2 = __shfl(v, 2);
    float w3 = __shfl(v, 3), w4 = __shfl(v, 4), w5 = __shfl(v, 5);
    float m2 = fmaxf(fmaxf(fmaxf(w0, w1), fmaxf(w2, w3)), fmaxf(w4, w5));
    float total = m2 + __logf(__expf(w0 - m2) + __expf(w1 - m2) + __expf(w2 - m2) +
                              __expf(w3 - m2) + __expf(w4 - m2) + __expf(w5 - m2));
    if (tid == 0) crfv[b] = total - real;
}

__global__ void k_sum(const float* __restrict__ crfv, float* __restrict__ out)
{
    __shared__ float red[4];
    int tid = threadIdx.x;
    float v = crfv[tid];
#pragma unroll
    for (int off = 32; off > 0; off >>= 1) v += __shfl_down(v, off);
    if ((tid & 63) == 0) red[tid >> 6] = v;
    __syncthreads();
    if (tid == 0) out[0] = red[0] + red[1] + red[2] + red[3];
}

extern "C" void kernel_launch(void* const* d_in, const int* in_sizes, int n_in,
                              void* d_out, int out_size, void* d_ws, size_t ws_size,
                              hipStream_t stream)
{
    const int* characters = (const int*)d_in[0];
    const int* tags       = (const int*)d_in[1];
    const int* length     = (const int*)d_in[2];
    const float* words    = (const float*)d_in[3];
    const float* emb      = (const float*)d_in[4];
    const float* w_ih_f   = (const float*)d_in[5];
    const float* w_hh_f   = (const float*)d_in[6];
    const float* b_ih_f   = (const float*)d_in[7];
    const float* b_hh_f   = (const float*)d_in[8];
    const float* w_ih_b   = (const float*)d_in[9];
    const float* w_hh_b   = (const float*)d_in[10];
    const float* b_ih_b   = (const float*)d_in[11];
    const float* b_hh_b   = (const float*)d_in[12];
    const float* w_lin_lstm = (const float*)d_in[13];
    const float* b_lin_lstm = (const float*)d_in[14];
    const float* conv1_w  = (const float*)d_in[15];
    const float* conv1_b  = (const float*)d_in[16];
    const float* bn1_s    = (const float*)d_in[17];
    const float* bn1_b    = (const float*)d_in[18];
    const float* conv2_w  = (const float*)d_in[19];
    const float* conv2_b  = (const float*)d_in[20];
    const float* bn2_s    = (const float*)d_in[21];
    const float* bn2_b    = (const float*)d_in[22];
    const float* conv3_w  = (const float*)d_in[23];
    const float* conv3_b  = (const float*)d_in[24];
    const float* bn3_s    = (const float*)d_in[25];
    const float* bn3_b    = (const float*)d_in[26];
    const float* w_lin_cnn = (const float*)d_in[27];
    const float* b_lin_cnn = (const float*)d_in[28];
    const float* w1       = (const float*)d_in[29];
    const float* b1       = (const float*)d_in[30];
    const float* w2       = (const float*)d_in[31];
    const float* b2       = (const float*)d_in[32];
    const float* w_tag    = (const float*)d_in[33];
    const float* b_tag    = (const float*)d_in[34];
    const float* trans    = (const float*)d_in[35];

    float* ws = (float*)d_ws;
    float* lstm_out = ws;                                  // B*L*H
    float* cat      = lstm_out + (size_t)B * LQ * H;       // B*L*256
    float* p1       = cat + (size_t)B * LQ * 256;          // B*16*12*32
    float* p2       = p1 + (size_t)B * 16 * 12 * 32;       // B*32*6*16
    float* p3       = p2 + (size_t)B * 32 * 6 * 16;        // B*1536
    float* logits   = p3 + (size_t)B * 1536;               // B*L*6
    float* crfv     = logits + (size_t)B * LQ * TT;        // 256
    float* h1b      = lstm_out;  // reuse: lstm_out dead after k_lstm_map

    k_lstm<<<512, 256, 0, stream>>>(characters, length, emb,
                                    w_ih_f, w_hh_f, b_ih_f, b_hh_f,
                                    w_ih_b, w_hh_b, b_ih_b, b_hh_b, lstm_out);
    k_conv1<<<6144, 256, 0, stream>>>(words, conv1_w, conv1_b, bn1_s, bn1_b, p1);
    k_conv2<<<512, 256, 0, stream>>>(p1, conv2_w, conv2_b, bn2_s, bn2_b, p2);
    k_conv3<<<512, 256, 0, stream>>>(p2, conv3_w, conv3_b, bn3_s, bn3_b, p3);
    k_lstm_map<<<512, 256, 0, stream>>>(lstm_out, length, w_lin_lstm, b_lin_lstm, cat);
    k_cnn_map<<<256, 256, 0, stream>>>(p3, length, w_lin_cnn, b_lin_cnn, cat);
    k_h1<<<512, 512, 0, stream>>>(cat, length, w1, b1, h1b);
    k_h2_logits<<<512, 256, 0, stream>>>(h1b, length, w2, b2, w_tag, b_tag, logits);
    k_crf<<<256, 64, 0, stream>>>(logits, tags, length, trans, crfv);
    k_sum<<<1, 256, 0, stream>>>(crfv, (float*)d_out);
}

// Round 10
// 768.159 us; speedup vs baseline: 2.8676x; 1.2185x over previous
//
#include <hip/hip_runtime.h>
#include <math.h>

#define B 256
#define LQ 300
#define V 20
#define CD 30
#define H 128
#define HH 64
#define TT 6
#define WN 48
#define WD 128
#define SLOPE 0.01f
#define START 4
#define STOP 5

__device__ __forceinline__ float fsig(float x) { return 1.0f / (1.0f + __expf(-x)); }
__device__ __forceinline__ float ftanh(float x) {
    x = fminf(fmaxf(x, -15.f), 15.f);
    float e = __expf(2.f * x);
    return (e - 1.f) / (e + 1.f);
}
__device__ __forceinline__ float lrelu(float x) { return x >= 0.f ? x : SLOPE * x; }

// ---------------- BiLSTM: one block per (sample, direction) ----------------
__global__ __launch_bounds__(256) void k_lstm(
    const int* __restrict__ chars, const int* __restrict__ length,
    const float* __restrict__ emb,
    const float* __restrict__ wihf, const float* __restrict__ whhf,
    const float* __restrict__ bihf, const float* __restrict__ bhhf,
    const float* __restrict__ wihb, const float* __restrict__ whhb,
    const float* __restrict__ bihb, const float* __restrict__ bhhb,
    float* __restrict__ lstm_out)
{
    __shared__ __align__(16) float emb_s[V * CD];
    __shared__ __align__(16) float pre_s[V * 256];
    __shared__ __align__(16) float h_s[2][HH];
    __shared__ int chars_s[LQ];
    int tid = threadIdx.x;
    int b = blockIdx.x >> 1;
    bool fwd = (blockIdx.x & 1) == 0;
    int gate = tid & 3, unit = tid >> 2;
    int row = gate * HH + unit;  // torch gate order i,f,g,o
    const float* wih = fwd ? wihf : wihb;
    const float* whh = fwd ? whhf : whhb;
    const float* bih = fwd ? bihf : bihb;
    const float* bhh = fwd ? bhhf : bhhb;
    for (int i = tid; i < V * CD; i += 256) emb_s[i] = emb[i];
    for (int i = tid; i < LQ; i += 256) chars_s[i] = chars[b * LQ + i];
    float wh[HH];
#pragma unroll
    for (int k = 0; k < HH; k++) wh[k] = whh[row * HH + k];
    float wi[CD];
#pragma unroll
    for (int k = 0; k < CD; k++) wi[k] = wih[row * CD + k];
    float bias = bih[row] + bhh[row];
    if (tid < 2 * HH) h_s[tid >> 6][tid & 63] = 0.f;
    int len = length[b];
    __syncthreads();
    // precompute vocab gate table (only V=20 distinct inputs)
    for (int v = 0; v < V; ++v) {
        float a0 = bias, a1 = 0.f;
        const float* ev = emb_s + v * CD;
#pragma unroll
        for (int k = 0; k < CD; k += 2) {
            a0 = fmaf(wi[k], ev[k], a0);
            a1 = fmaf(wi[k + 1], ev[k + 1], a1);
        }
        pre_s[v * 256 + tid] = a0 + a1;
    }
    __syncthreads();
    float c = 0.f;
    int hofs = fwd ? 0 : HH;
    int lane = tid & 63, qbase = lane & ~3;
    int src0 = fwd ? 0 : (len - 1);
    float accx = pre_s[chars_s[src0] * 256 + tid];
    for (int t = 0; t < len; ++t) {
        int buf = t & 1;  // read h_s[buf], write h_s[1-buf]
        float acc_cur = accx;
        if (t + 1 < len) {
            int srcn = fwd ? (t + 1) : (len - 2 - t);
            accx = pre_s[chars_s[srcn] * 256 + tid];
        }
        const float4* hp4 = (const float4*)h_s[buf];
        float a0 = acc_cur, a1 = 0.f, a2 = 0.f, a3 = 0.f;
#pragma unroll
        for (int k4 = 0; k4 < 16; k4++) {
            float4 hv4 = hp4[k4];
            a0 = fmaf(wh[4 * k4], hv4.x, a0);
            a1 = fmaf(wh[4 * k4 + 1], hv4.y, a1);
            a2 = fmaf(wh[4 * k4 + 2], hv4.z, a2);
            a3 = fmaf(wh[4 * k4 + 3], hv4.w, a3);
        }
        float x = (a0 + a1) + (a2 + a3);
        float y = (gate == 2) ? 2.f * x : x;
        float s = 1.f / (1.f + __expf(-y));
        float a = (gate == 2) ? (2.f * s - 1.f) : s;
        float gi = __shfl(a, qbase + 0);
        float gf = __shfl(a, qbase + 1);
        float gg = __shfl(a, qbase + 2);
        float go = __shfl(a, qbase + 3);
        c = gf * c + gi * gg;
        float hv = go * ftanh(c);
        if (gate == 0) {
            int src = fwd ? t : (len - 1 - t);
            h_s[1 - buf][unit] = hv;
            lstm_out[((size_t)b * LQ + src) * H + hofs + unit] = hv;
        }
        __syncthreads();
    }
}

// ---------------- lstm_mapping: K split 2x64, FULL unroll (w stays in VGPRs), 8 rows/iter ----------------
__global__ __launch_bounds__(256) void k_lstm_map(
    const float* __restrict__ lstm_out, const int* __restrict__ length,
    const float* __restrict__ wl, const float* __restrict__ bl,
    float* __restrict__ cat)
{
    __shared__ __align__(16) float row_s[8][128];
    __shared__ float part_s[2][8][128];
    __shared__ float b_s[128];
    int tid = threadIdx.x;
    int b = blockIdx.x >> 1, half = blockIdx.x & 1;
    int h = tid & 127, kh = tid >> 7;
    float w[64];
#pragma unroll
    for (int k = 0; k < 64; k++) w[k] = wl[h * 128 + kh * 64 + k];
    if (tid < 128) b_s[tid] = bl[tid];
    int len = length[b];
    const float* src = lstm_out + (size_t)b * LQ * H;
    float* dst = cat + (size_t)b * LQ * 256;
    int nrows = (len - half + 1) >> 1;  // t = half + 2*ri
    for (int base = 0; base < nrows; base += 8) {
        __syncthreads();
        for (int i = tid; i < 8 * 128; i += 256) {
            int ri = i >> 7, k = i & 127;
            int rr = base + ri;
            if (rr < nrows) row_s[ri][k] = src[(size_t)(half + 2 * rr) * H + k];
        }
        __syncthreads();
        float acc[8];
#pragma unroll
        for (int r = 0; r < 8; r++) acc[r] = 0.f;
#pragma unroll
        for (int k4 = 0; k4 < 16; k4++) {
#pragma unroll
            for (int r = 0; r < 8; r++) {
                float4 x = ((const float4*)(row_s[r] + kh * 64))[k4];
                acc[r] = fmaf(w[4 * k4], x.x, acc[r]);
                acc[r] = fmaf(w[4 * k4 + 1], x.y, acc[r]);
                acc[r] = fmaf(w[4 * k4 + 2], x.z, acc[r]);
                acc[r] = fmaf(w[4 * k4 + 3], x.w, acc[r]);
            }
        }
#pragma unroll
        for (int r = 0; r < 8; r++) part_s[kh][r][h] = acc[r];
        __syncthreads();
        for (int i = tid; i < 1024; i += 256) {
            int r = i >> 7, o = i & 127;
            int rr = base + r;
            if (rr < nrows)
                dst[(size_t)(half + 2 * rr) * 256 + o] =
                    lrelu(b_s[o] + part_s[0][r][o] + part_s[1][r][o]);
        }
    }
}

// ---------------- conv1 + bn + leaky + pool: [B,1,48,128] -> [B,16,12,32] ----------------
__global__ void k_conv1(const float* __restrict__ words,
                        const float* __restrict__ cw, const float* __restrict__ cb,
                        const float* __restrict__ bs, const float* __restrict__ bb,
                        float* __restrict__ p1)
{
    int idx = blockIdx.x * 256 + threadIdx.x;  // B*16*12*32
    int px = idx & 31;
    int t1 = idx >> 5;
    int py = t1 % 12;
    int t2 = t1 / 12;
    int oc = t2 & 15;
    int b = t2 >> 4;
    float w[9];
#pragma unroll
    for (int k = 0; k < 9; k++) w[k] = cw[oc * 9 + k];
    float patch[5][5];
    int iy0 = 4 * py - 1, ix0 = 4 * px - 1;
#pragma unroll
    for (int r = 0; r < 5; r++)
#pragma unroll
        for (int cc = 0; cc < 5; cc++) {
            int iy = iy0 + r, ix = ix0 + cc;
            patch[r][cc] = (iy >= 0 && iy < WN && ix >= 0 && ix < WD)
                               ? words[((size_t)b * WN + iy) * WD + ix] : 0.f;
        }
    float bias = cb[oc], s = bs[oc], sb = bb[oc];
    float best = -1e30f;
#pragma unroll
    for (int dy = 0; dy < 2; dy++)
#pragma unroll
        for (int dx = 0; dx < 2; dx++) {
            float acc = bias;
#pragma unroll
            for (int ky = 0; ky < 3; ky++)
#pragma unroll
                for (int kx = 0; kx < 3; kx++)
                    acc = fmaf(w[ky * 3 + kx], patch[2 * dy + ky][2 * dx + kx], acc);
            best = fmaxf(best, lrelu(acc * s + sb));
        }
    p1[idx] = best;
}

// ---------------- conv2: LDS-staged, 2 blocks/sample (16 oc each) ----------------
__global__ __launch_bounds__(256) void k_conv2(
    const float* __restrict__ p1,
    const float* __restrict__ cw, const float* __restrict__ cb,
    const float* __restrict__ bs, const float* __restrict__ bb,
    float* __restrict__ p2)
{
    __shared__ float in_s[16 * 14 * 34];  // padded [16][14][34]
    __shared__ float w_s[16 * 16 * 9];
    int tid = threadIdx.x;
    int b = blockIdx.x >> 1;
    int oh = (blockIdx.x & 1) << 4;  // oc base 0 or 16
    for (int i = tid; i < 16 * 14 * 34; i += 256) in_s[i] = 0.f;
    for (int i = tid; i < 16 * 16 * 9; i += 256) w_s[i] = cw[oh * 16 * 9 + i];
    __syncthreads();
    for (int i = tid; i < 16 * 12 * 32; i += 256) {
        int ic = i / 384;
        int r = i - ic * 384;
        int iy = r >> 5, ix = r & 31;
        in_s[ic * 476 + (iy + 1) * 34 + ix + 1] = p1[b * 6144 + i];
    }
    __syncthreads();
    int ocl = tid >> 4;       // 0..15
    int l16 = tid & 15;       // spatial lane
    float acc[6][4];
    float bias = cb[oh + ocl];
#pragma unroll
    for (int q = 0; q < 6; q++)
#pragma unroll
        for (int j = 0; j < 4; j++) acc[q][j] = bias;
    for (int ic = 0; ic < 16; ic++) {
        const float* wp = w_s + (ocl * 16 + ic) * 9;
        float w[9];
#pragma unroll
        for (int k = 0; k < 9; k++) w[k] = wp[k];
        const float* ip = in_s + ic * 476;
#pragma unroll
        for (int q = 0; q < 6; q++) {
            int sp = l16 + (q << 4);
            int py = sp >> 4, px = sp & 15;
            const float* pb = ip + (2 * py) * 34 + 2 * px;
            float patch[4][4];
#pragma unroll
            for (int r = 0; r < 4; r++)
#pragma unroll
                for (int cc = 0; cc < 4; cc++) patch[r][cc] = pb[r * 34 + cc];
#pragma unroll
            for (int dy = 0; dy < 2; dy++)
#pragma unroll
                for (int dx = 0; dx < 2; dx++) {
                    float a = 0.f;
#pragma unroll
                    for (int ky = 0; ky < 3; ky++)
#pragma unroll
                        for (int kx = 0; kx < 3; kx++)
                            a = fmaf(w[ky * 3 + kx], patch[dy + ky][dx + kx], a);
                    acc[q][dy * 2 + dx] += a;
                }
        }
    }
    float s = bs[oh + ocl], sb = bb[oh + ocl];
#pragma unroll
    for (int q = 0; q < 6; q++) {
        float best = -1e30f;
#pragma unroll
        for (int j = 0; j < 4; j++) best = fmaxf(best, lrelu(acc[q][j] * s + sb));
        int sp = l16 + (q << 4);
        p2[((size_t)b * 32 + oh + ocl) * 96 + sp] = best;
    }
}

// ---------------- conv3: LDS-staged, 2 blocks/sample (32 oc each) ----------------
__global__ __launch_bounds__(256) void k_conv3(
    const float* __restrict__ p2,
    const float* __restrict__ cw, const float* __restrict__ cb,
    const float* __restrict__ bs, const float* __restrict__ bb,
    float* __restrict__ p3)
{
    __shared__ float in_s[32 * 8 * 18];   // padded [32][8][18]
    __shared__ float w_s[32 * 32 * 9];
    int tid = threadIdx.x;
    int b = blockIdx.x >> 1;
    int oh = (blockIdx.x & 1) << 5;  // oc base 0 or 32
    for (int i = tid; i < 32 * 8 * 18; i += 256) in_s[i] = 0.f;
    for (int i = tid; i < 32 * 32 * 9; i += 256) w_s[i] = cw[oh * 32 * 9 + i];
    __syncthreads();
    for (int i = tid; i < 32 * 6 * 16; i += 256) {
        int ic = i / 96;
        int r = i - ic * 96;
        int iy = r >> 4, ix = r & 15;
        in_s[ic * 144 + (iy + 1) * 18 + ix + 1] = p2[b * 3072 + i];
    }
    __syncthreads();
    int ocl = tid >> 3;      // 0..31
    int l8 = tid & 7;
    float acc[3][4];
    float bias = cb[oh + ocl];
#pragma unroll
    for (int q = 0; q < 3; q++)
#pragma unroll
        for (int j = 0; j < 4; j++) acc[q][j] = bias;
    for (int ic = 0; ic < 32; ic++) {
        const float* wp = w_s + (ocl * 32 + ic) * 9;
        float w[9];
#pragma unroll
        for (int k = 0; k < 9; k++) w[k] = wp[k];
        const float* ip = in_s + ic * 144;
#pragma unroll
        for (int q = 0; q < 3; q++) {
            int sp = l8 + (q << 3);
            int py = sp >> 3, px = sp & 7;
            const float* pb = ip + (2 * py) * 18 + 2 * px;
            float patch[4][4];
#pragma unroll
            for (int r = 0; r < 4; r++)
#pragma unroll
                for (int cc = 0; cc < 4; cc++) patch[r][cc] = pb[r * 18 + cc];
#pragma unroll
            for (int dy = 0; dy < 2; dy++)
#pragma unroll
                for (int dx = 0; dx < 2; dx++) {
                    float a = 0.f;
#pragma unroll
                    for (int ky = 0; ky < 3; ky++)
#pragma unroll
                        for (int kx = 0; kx < 3; kx++)
                            a = fmaf(w[ky * 3 + kx], patch[dy + ky][dx + kx], a);
                    acc[q][dy * 2 + dx] += a;
                }
        }
    }
    float s = bs[oh + ocl], sb = bb[oh + ocl];
#pragma unroll
    for (int q = 0; q < 3; q++) {
        float best = -1e30f;
#pragma unroll
        for (int j = 0; j < 4; j++) best = fmaxf(best, lrelu(acc[q][j] * s + sb));
        int sp = l8 + (q << 3);
        p3[((size_t)b * 64 + oh + ocl) * 24 + sp] = best;
    }
}

// ---------------- cnn_mapping with the [B,128,300]->[B,300,128] reshape quirk ----------------
__global__ __launch_bounds__(256) void k_cnn_map(
    const float* __restrict__ p3, const int* __restrict__ length,
    const float* __restrict__ wlc, const float* __restrict__ blc,
    float* __restrict__ cat)
{
    __shared__ float flat_s[1536];
    __shared__ float w_s[3600];
    __shared__ float b_s[300];
    int tid = threadIdx.x, b = blockIdx.x;
    for (int i = tid; i < 1536; i += 256) flat_s[i] = p3[b * 1536 + i];
    for (int i = tid; i < 3600; i += 256) w_s[i] = wlc[i];
    for (int i = tid; i < 300; i += 256) b_s[i] = blc[i];
    int len = length[b];
    __syncthreads();
    int bound = len * 128;
    for (int j = tid; j < bound; j += 256) {
        int l = j >> 7, h = j & 127;
        int row = j / 300, col = j - row * 300;
        float acc = b_s[col];
#pragma unroll
        for (int k = 0; k < 12; k++) acc = fmaf(flat_s[row * 12 + k], w_s[col * 12 + k], acc);
        cat[((size_t)b * LQ + l) * 256 + H + h] = lrelu(acc);
    }
}

// ---------------- h1: K split 4x64, FULL unroll (w stays in VGPRs), 8 rows/iter, 512 threads ----------------
__global__ __launch_bounds__(512) void k_h1(
    const float* __restrict__ cat, const int* __restrict__ length,
    const float* __restrict__ w1, const float* __restrict__ b1,
    float* __restrict__ h1b)
{
    __shared__ __align__(16) float row_s[8][256];
    __shared__ float part_s[4][8][104];
    __shared__ float b_s[100];
    int tid = threadIdx.x;
    int b = blockIdx.x >> 1, half = blockIdx.x & 1;
    int lane = tid & 127, q = tid >> 7;  // q = K quarter 0..3
    bool act = lane < 100;
    float w[64];
    if (act) {
#pragma unroll
        for (int k = 0; k < 64; k++) w[k] = w1[lane * 256 + q * 64 + k];
    }
    if (tid < 100) b_s[tid] = b1[tid];
    int len = length[b];
    const float* src = cat + (size_t)b * LQ * 256;
    float* dst = h1b + (size_t)b * LQ * 100;
    int nrows = (len - half + 1) >> 1;
    for (int base = 0; base < nrows; base += 8) {
        __syncthreads();
        for (int i = tid; i < 8 * 256; i += 512) {
            int ri = i >> 8, k = i & 255;
            int rr = base + ri;
            if (rr < nrows) row_s[ri][k] = src[(size_t)(half + 2 * rr) * 256 + k];
        }
        __syncthreads();
        if (act) {
            float acc[8];
#pragma unroll
            for (int r = 0; r < 8; r++) acc[r] = 0.f;
#pragma unroll
            for (int k4 = 0; k4 < 16; k4++) {
#pragma unroll
                for (int r = 0; r < 8; r++) {
                    float4 x = ((const float4*)(row_s[r] + q * 64))[k4];
                    acc[r] = fmaf(w[4 * k4], x.x, acc[r]);
                    acc[r] = fmaf(w[4 * k4 + 1], x.y, acc[r]);
                    acc[r] = fmaf(w[4 * k4 + 2], x.z, acc[r]);
                    acc[r] = fmaf(w[4 * k4 + 3], x.w, acc[r]);
                }
            }
#pragma unroll
            for (int r = 0; r < 8; r++) part_s[q][r][lane] = acc[r];
        }
        __syncthreads();
        for (int i = tid; i < 800; i += 512) {
            int r = i / 100, o = i - r * 100;
            int rr = base + r;
            if (rr < nrows)
                dst[(size_t)(half + 2 * rr) * 100 + o] =
                    lrelu(b_s[o] + (part_s[0][r][o] + part_s[1][r][o]) +
                          (part_s[2][r][o] + part_s[3][r][o]));
        }
    }
}

// ---------------- h2 + logits: K split 2x52 zero-padded, FULL unroll, 8 rows/iter ----------------
__global__ __launch_bounds__(256) void k_h2_logits(
    const float* __restrict__ h1b, const int* __restrict__ length,
    const float* __restrict__ w2, const float* __restrict__ b2,
    const float* __restrict__ wt, const float* __restrict__ bt,
    float* __restrict__ logits)
{
    __shared__ __align__(16) float row_s[8][104];   // K=100 padded to 104 (zeros)
    __shared__ float part_s[2][8][96];
    __shared__ float h2_s[8][96];
    __shared__ float wt_s[6 * 94];
    __shared__ float bt_s[6];
    __shared__ float b2_s[94];
    int tid = threadIdx.x;
    int b = blockIdx.x >> 1, half = blockIdx.x & 1;
    int o = tid & 127, kh = tid >> 7;
    bool act = o < 94;
    int kbase = kh * 52;  // kh=0: k 0..51, kh=1: k 52..103 (100..103 are zero pad)
    float w[52];
    if (act) {
#pragma unroll
        for (int k = 0; k < 52; k++)
            w[k] = (kbase + k < 100) ? w2[o * 100 + kbase + k] : 0.f;
    }
    if (tid < 94) b2_s[tid] = b2[tid];
    for (int i = tid; i < 564; i += 256) wt_s[i] = wt[i];
    if (tid < 6) bt_s[tid] = bt[tid];
    int len = length[b];
    const float* src = h1b + (size_t)b * LQ * 100;
    float* dst = logits + (size_t)b * LQ * TT;
    int nrows = (len - half + 1) >> 1;
    for (int base = 0; base < nrows; base += 8) {
        __syncthreads();
        for (int i = tid; i < 8 * 104; i += 256) {
            int r = i / 104, k = i - r * 104;
            int rr = base + r;
            row_s[r][k] = (k < 100 && rr < nrows) ? src[(size_t)(half + 2 * rr) * 100 + k] : 0.f;
        }
        __syncthreads();
        if (act) {
            float acc[8];
#pragma unroll
            for (int r = 0; r < 8; r++) acc[r] = 0.f;
#pragma unroll
            for (int k4 = 0; k4 < 13; k4++) {
#pragma unroll
                for (int r = 0; r < 8; r++) {
                    float4 x = ((const float4*)(row_s[r] + kbase))[k4];
                    acc[r] = fmaf(w[4 * k4], x.x, acc[r]);
                    acc[r] = fmaf(w[4 * k4 + 1], x.y, acc[r]);
                    acc[r] = fmaf(w[4 * k4 + 2], x.z, acc[r]);
                    acc[r] = fmaf(w[4 * k4 + 3], x.w, acc[r]);
                }
            }
#pragma unroll
            for (int r = 0; r < 8; r++) part_s[kh][r][o] = acc[r];
        }
        __syncthreads();
        for (int i = tid; i < 752; i += 256) {
            int r = i / 94, oo = i - r * 94;
            h2_s[r][oo] = lrelu(b2_s[oo] + part_s[0][r][oo] + part_s[1][r][oo]);
        }
        __syncthreads();
        if (tid < 48) {
            int r = tid / 6, tag = tid - r * 6;
            int rr = base + r;
            if (rr < nrows) {
                float a0 = bt_s[tag], a1 = 0.f;
#pragma unroll
                for (int k = 0; k < 94; k += 2) {
                    a0 = fmaf(wt_s[tag * 94 + k], h2_s[r][k], a0);
                    a1 = fmaf(wt_s[tag * 94 + k + 1], h2_s[r][k + 1], a1);
                }
                dst[(size_t)(half + 2 * rr) * TT + tag] = lrelu(a0 + a1);
            }
        }
    }
}

// ---------------- CRF: real score + alpha recursion, one wave per sample ----------------
__global__ __launch_bounds__(64) void k_crf(
    const float* __restrict__ logits, const int* __restrict__ tags,
    const int* __restrict__ length, const float* __restrict__ trans,
    float* __restrict__ crfv)
{
    int tid = threadIdx.x, b = blockIdx.x;
    int len = length[b];
    const int* tg = tags + b * LQ;
    float s = 0.f;
    for (int t = tid; t < len; t += 64) {
        int cur = tg[t];
        int prev = (t == 0) ? START : tg[t - 1];
        s += logits[((size_t)b * LQ + t) * TT + cur] + trans[prev * TT + cur];
    }
#pragma unroll
    for (int off = 32; off > 0; off >>= 1) s += __shfl_down(s, off);
    float real = __shfl(s, 0) + trans[tg[len - 1] * TT + STOP];
    int j = (tid < TT) ? tid : 0;
    float trc[TT];
#pragma unroll
    for (int i = 0; i < TT; i++) trc[i] = trans[i * TT + j];
    float tstop = trans[j * TT + STOP];
    float alpha = 0.f;
    for (int t = 0; t < len; ++t) {
        float lg = logits[((size_t)b * LQ + t) * TT + j];
        float a0 = __shfl(alpha, 0), a1 = __shfl(alpha, 1), a2 = __shfl(alpha, 2);
        float a3 = __shfl(alpha, 3), a4 = __shfl(alpha, 4), a5 = __shfl(alpha, 5);
        float v0 = a0 + trc[0], v1 = a1 + trc[1], v2 = a2 + trc[2];
        float v3 = a3 + trc[3], v4 = a4 + trc[4], v5 = a5 + trc[5];
        float m = fmaxf(fmaxf(fmaxf(v0, v1), fmaxf(v2, v3)), fmaxf(v4, v5));
        float sum = __expf(v0 - m) + __expf(v1 - m) + __expf(v2 - m) +
                    __expf(v3 - m) + __expf(v4 - m) + __expf(v5 - m);
        alpha = m + __logf(sum) + lg;
    }
    float v = alpha + tstop;
    float w0 = __shfl(v, 0), w1 = __shfl(v, 1), w2 = __shfl(v, 2);
    float w3 = __shfl(v, 3), w4 = __shfl(v, 4), w5 = __shfl(v, 5);
    float m2 = fmaxf(fmaxf(fmaxf(w0, w1), fmaxf(w2, w3)), fmaxf(w4, w5));
    float total = m2 + __logf(__expf(w0 - m2) + __expf(w1 - m2) + __expf(w2 - m2) +
                              __expf(w3 - m2) + __expf(w4 - m2) + __expf(w5 - m2));
    if (tid == 0) crfv[b] = total - real;
}

__global__ void k_sum(const float* __restrict__ crfv, float* __restrict__ out)
{
    __shared__ float red[4];
    int tid = threadIdx.x;
    float v = crfv[tid];
#pragma unroll
    for (int off = 32; off > 0; off >>= 1) v += __shfl_down(v, off);
    if ((tid & 63) == 0) red[tid >> 6] = v;
    __syncthreads();
    if (tid == 0) out[0] = red[0] + red[1] + red[2] + red[3];
}

extern "C" void kernel_launch(void* const* d_in, const int* in_sizes, int n_in,
                              void* d_out, int out_size, void* d_ws, size_t ws_size,
                              hipStream_t stream)
{
    const int* characters = (const int*)d_in[0];
    const int* tags       = (const int*)d_in[1];
    const int* length     = (const int*)d_in[2];
    const float* words    = (const float*)d_in[3];
    const float* emb      = (const float*)d_in[4];
    const float* w_ih_f   = (const float*)d_in[5];
    const float* w_hh_f   = (const float*)d_in[6];
    const float* b_ih_f   = (const float*)d_in[7];
    const float* b_hh_f   = (const float*)d_in[8];
    const float* w_ih_b   = (const float*)d_in[9];
    const float* w_hh_b   = (const float*)d_in[10];
    const float* b_ih_b   = (const float*)d_in[11];
    const float* b_hh_b   = (const float*)d_in[12];
    const float* w_lin_lstm = (const float*)d_in[13];
    const float* b_lin_lstm = (const float*)d_in[14];
    const float* conv1_w  = (const float*)d_in[15];
    const float* conv1_b  = (const float*)d_in[16];
    const float* bn1_s    = (const float*)d_in[17];
    const float* bn1_b    = (const float*)d_in[18];
    const float* conv2_w  = (const float*)d_in[19];
    const float* conv2_b  = (const float*)d_in[20];
    const float* bn2_s    = (const float*)d_in[21];
    const float* bn2_b    = (const float*)d_in[22];
    const float* conv3_w  = (const float*)d_in[23];
    const float* conv3_b  = (const float*)d_in[24];
    const float* bn3_s    = (const float*)d_in[25];
    const float* bn3_b    = (const float*)d_in[26];
    const float* w_lin_cnn = (const float*)d_in[27];
    const float* b_lin_cnn = (const float*)d_in[28];
    const float* w1       = (const float*)d_in[29];
    const float* b1       = (const float*)d_in[30];
    const float* w2       = (const float*)d_in[31];
    const float* b2       = (const float*)d_in[32];
    const float* w_tag    = (const float*)d_in[33];
    const float* b_tag    = (const float*)d_in[34];
    const float* trans    = (const float*)d_in[35];

    float* ws = (float*)d_ws;
    float* lstm_out = ws;                                  // B*L*H
    float* cat      = lstm_out + (size_t)B * LQ * H;       // B*L*256
    float* p1       = cat + (size_t)B * LQ * 256;          // B*16*12*32
    float* p2       = p1 + (size_t)B * 16 * 12 * 32;       // B*32*6*16
    float* p3       = p2 + (size_t)B * 32 * 6 * 16;        // B*1536
    float* logits   = p3 + (size_t)B * 1536;               // B*L*6
    float* crfv     = logits + (size_t)B * LQ * TT;        // 256
    float* h1b      = lstm_out;  // reuse: lstm_out dead after k_lstm_map

    k_lstm<<<512, 256, 0, stream>>>(characters, length, emb,
                                    w_ih_f, w_hh_f, b_ih_f, b_hh_f,
                                    w_ih_b, w_hh_b, b_ih_b, b_hh_b, lstm_out);
    k_conv1<<<6144, 256, 0, stream>>>(words, conv1_w, conv1_b, bn1_s, bn1_b, p1);
    k_conv2<<<512, 256, 0, stream>>>(p1, conv2_w, conv2_b, bn2_s, bn2_b, p2);
    k_conv3<<<512, 256, 0, stream>>>(p2, conv3_w, conv3_b, bn3_s, bn3_b, p3);
    k_lstm_map<<<512, 256, 0, stream>>>(lstm_out, length, w_lin_lstm, b_lin_lstm, cat);
    k_cnn_map<<<256, 256, 0, stream>>>(p3, length, w_lin_cnn, b_lin_cnn, cat);
    k_h1<<<512, 512, 0, stream>>>(cat, length, w1, b1, h1b);
    k_h2_logits<<<512, 256, 0, stream>>>(h1b, length, w2, b2, w_tag, b_tag, logits);
    k_crf<<<256, 64, 0, stream>>>(logits, tags, length, trans, crfv);
    k_sum<<<1, 256, 0, stream>>>(crfv, (float*)d_out);
}